// Round 17
// baseline (740.244 us; speedup 1.0000x reference)
//
#include <hip/hip_runtime.h>
#include <hip/hip_bf16.h>

typedef unsigned int u32;
typedef unsigned long long u64;
typedef float v2f __attribute__((ext_vector_type(2)));
typedef float v4f __attribute__((ext_vector_type(4)));

// ---------------- workspace layout (bytes) ----------------
#define OFF_Y      0ull             // 8,388,608
#define OFF_WT     8388608ull       // 9,437,184 -> end 17,825,792
#define OFF_ZPART  8388608ull       // 4*45*4096*4 = 2,949,120
#define OFF_SCORES 11337728ull      // 147,456
#define OFF_DRAW   11485184ull      // 589,824
#define OFF_HIST   12075008ull      // 524,288
#define OFF_TOPV   12665344ull      // 24,576
#define OFF_BOXES  12714496ull      // 98,304
#define OFF_VW     12812800ull      // 1,024
#define OFF_MASK   12813824ull      // 6000*96*8 = 4,608,000 -> 17,421,824

#define NS     36864
#define PRE    6000
#define POST   300
#define SORTN  8192
#define MROW   96   // mask words per row (94 used)
#define NBW    16   // nms batch: rows in flight

// ====== K0 (v17): LDS-tiled transpose gw[co][ci*9+k] -> wT[ci][k][co] =======
__global__ __launch_bounds__(256) void k_wtrans(const float* __restrict__ gw,
                                                float* __restrict__ wT) {
    __shared__ float tile[64][65];
    const int t = threadIdx.x;
    const int tr = t & 63;
    const int tc = t >> 6;
    const int bco = (blockIdx.x & 7) << 6;
    const int brr = (blockIdx.x >> 3) << 6;

#pragma unroll
    for (int i = 0; i < 16; ++i) {
        int row = tc + (i << 2);
        tile[row][tr] = gw[(size_t)(bco + row) * 4608 + brr + tr];
    }
    __syncthreads();
#pragma unroll
    for (int i = 0; i < 16; ++i) {
        int rl = tc + (i << 2);
        int rg = brr + rl;
        int ci = rg / 9;
        int k = rg - ci * 9;
        wT[(size_t)ci * 4608 + k * 512 + bco + tr] = tile[tr][rl];
    }
}

// ================= K1: 3x3 conv 512->512 + bias + relu (v22) ================
// v15 signature: VALU 59%, VGPR 12, LDS 0, but grid-capped at 4 waves/SIMD --
// the 41% idle is lgkm waits on per-ci weight s_loads. v22: wave = 4 co,
// grid 2048 = 32 co-blk x 64 h -> 8 blocks/CU = 8 waves/SIMD. Per-CU K$
// dwords/ci conserved (8blk x 4wv x 36 = 4blk x 4wv x 72); only x L2 traffic
// doubles (~24us aggregate, hidden). NOT v8 redux: no LDS staging, no DS
// pipe, conserved K$ traffic. Per-output FMA order (ci 0..511, k 0..8)
// unchanged -> bit-exact.
__device__ __forceinline__ float dpp_shr1(float v) {
    return __int_as_float(__builtin_amdgcn_update_dpp(
        0, __float_as_int(v), 0x138, 0xF, 0xF, true));
}
__device__ __forceinline__ float dpp_shl1(float v) {
    return __int_as_float(__builtin_amdgcn_update_dpp(
        0, __float_as_int(v), 0x130, 0xF, 0xF, true));
}
__global__ __launch_bounds__(256, 8) void k_conv1(const float* __restrict__ x,
                                                  const float* __restrict__ wT,
                                                  const float* __restrict__ gb,
                                                  float* __restrict__ y) {
    const int t = threadIdx.x;
    const int tx = t & 63;
    const int wv = __builtin_amdgcn_readfirstlane(t >> 6);
    const int cob = (blockIdx.x & 31) << 4;   // 32 co-blocks x 16 co
    const int h0 = blockIdx.x >> 5;           // 0..63
    const int co_base = cob + (wv << 2);      // 4 co per wave

    const bool rv0 = (h0 > 0);
    const bool rv2 = (h0 < 63);
    const float* xp0 = x + (rv0 ? (h0 - 1) : h0) * 64 + tx;
    const float* xp1 = x + h0 * 64 + tx;
    const float* xp2 = x + (rv2 ? (h0 + 1) : h0) * 64 + tx;

    v2f acc2[2];
#pragma unroll
    for (int j = 0; j < 2; ++j) acc2[j] = (v2f){0.f, 0.f};

#pragma unroll 2
    for (int ci = 0; ci < 512; ++ci) {
        float c0 = xp0[(size_t)ci * 4096];
        float c1 = xp1[(size_t)ci * 4096];
        float c2 = xp2[(size_t)ci * 4096];
        c0 = rv0 ? c0 : 0.f;
        c2 = rv2 ? c2 : 0.f;
        float xr[9];
        xr[0] = dpp_shr1(c0); xr[1] = c0; xr[2] = dpp_shl1(c0);
        xr[3] = dpp_shr1(c1); xr[4] = c1; xr[5] = dpp_shl1(c1);
        xr[6] = dpp_shr1(c2); xr[7] = c2; xr[8] = dpp_shl1(c2);

        // wT[ci][k][co]: wave's 4 co = 2 consecutive v2f per k (one dwordx4)
        const v2f* wk2 = (const v2f*)(wT + (size_t)ci * 4608 + co_base);
#pragma unroll
        for (int k = 0; k < 9; ++k) {
            v2f w0 = wk2[k * 256 + 0];
            v2f w1 = wk2[k * 256 + 1];
            float xv = xr[k];
            v2f xpv = {xv, xv};
            acc2[0] = __builtin_elementwise_fma(w0, xpv, acc2[0]);
            acc2[1] = __builtin_elementwise_fma(w1, xpv, acc2[1]);
        }
    }

#pragma unroll
    for (int j = 0; j < 2; ++j) {
        int co0 = co_base + 2 * j;
        float v0 = acc2[j].x + gb[co0];
        float v1 = acc2[j].y + gb[co0 + 1];
        v0 = v0 > 0.f ? v0 : 0.f;
        v1 = v1 > 0.f ? v1 : 0.f;
        y[co0 * 4096 + (h0 << 6) + tx] = v0;
        y[(co0 + 1) * 4096 + (h0 << 6) + tx] = v1;
    }
}

// ================= K2a: 1x1 heads, partial over ci quarters (9.3 us) ========
__global__ __launch_bounds__(256) void k_heads_part(const float* __restrict__ y,
                                                    const float* __restrict__ cw,
                                                    const float* __restrict__ bw,
                                                    float* __restrict__ zpart,
                                                    u32* __restrict__ hist) {
    __shared__ __align__(16) float ys[64][132];
    const int t = threadIdx.x;
    {
        int hb = blockIdx.x << 9;
        hist[hb + t] = 0u;
        hist[hb + 256 + t] = 0u;
    }
    const int px = t & 63;
    const int gu = __builtin_amdgcn_readfirstlane(t >> 6);
    const int px0 = (blockIdx.x & 63) << 6;
    const int q = blockIdx.x >> 6;
    const int cib = q << 7;
    const int nch = (gu == 0) ? 12 : 11;

    const float* wrow[12];
#pragma unroll
    for (int j = 0; j < 12; ++j) {
        int ch = gu + 4 * j;
        if (ch < 9) wrow[j] = cw + ch * 512;
        else if (ch < 45) wrow[j] = bw + (ch - 9) * 512;
        else wrow[j] = cw;
    }
    float acc[12];
#pragma unroll
    for (int j = 0; j < 12; ++j) acc[j] = 0.f;

    for (int idx = t; idx < 128 * 64; idx += 256) {
        int ci = idx >> 6;
        int pp = idx & 63;
        ys[pp][ci] = y[(cib + ci) * 4096 + px0 + pp];
    }
    __syncthreads();

#pragma unroll 1
    for (int cq = 0; cq < 32; ++cq) {
        float4 yv = *(const float4*)&ys[px][cq << 2];
        float4 wv[12];
#pragma unroll
        for (int j = 0; j < 12; ++j)
            if (j < nch) wv[j] = *(const float4*)(wrow[j] + cib + (cq << 2));
#pragma unroll
        for (int j = 0; j < 12; ++j)
            if (j < nch)
                acc[j] += wv[j].x * yv.x + wv[j].y * yv.y + wv[j].z * yv.z + wv[j].w * yv.w;
    }
    for (int j = 0; j < nch; ++j) {
        int ch = gu + 4 * j;
        zpart[((q * 45 + ch) << 12) + px0 + px] = acc[j];
    }
}

// ================= K2b: reduce partials + bias + sigmoid + hist =============
__global__ __launch_bounds__(256) void k_hreduce(const float* __restrict__ zpart,
                                                 const float* __restrict__ cb,
                                                 const float* __restrict__ bb,
                                                 float* __restrict__ scores,
                                                 float* __restrict__ draw,
                                                 u32* __restrict__ hist) {
    int i = blockIdx.x * 256 + threadIdx.x;
    if (i >= 45 * 4096) return;
    int ch = i >> 12;
    int sp = i & 4095;
    float z = zpart[((0 * 45 + ch) << 12) + sp] + zpart[((1 * 45 + ch) << 12) + sp] +
              zpart[((2 * 45 + ch) << 12) + sp] + zpart[((3 * 45 + ch) << 12) + sp];
    if (ch < 9) {
        z += cb[ch];
        float s = 1.f / (1.f + expf(-z));
        scores[(ch << 12) + sp] = s;
        u32 sb = __float_as_uint(s);
        atomicAdd(&hist[sb >> 13], 1u);
    } else {
        z += bb[ch - 9];
        draw[((ch - 9) << 12) + sp] = z;
    }
}

// ======== K3 (v18): hist-scan + compact + bitonic sort + decode (99 us) =====
__global__ __launch_bounds__(1024) void k_select(const u32* __restrict__ hist,
                                                 const float* __restrict__ scores,
                                                 const float* __restrict__ draw,
                                                 const float* __restrict__ anchors,
                                                 const int* __restrict__ ishape,
                                                 float* __restrict__ boxes,
                                                 float* __restrict__ topv,
                                                 u64* __restrict__ vw) {
    __shared__ u32 csum[1024];
    __shared__ u32 suf[1024];
    __shared__ u64 sk[SORTN];   // 64 KB
    __shared__ int sel_s, cnt_s;
    const int t = threadIdx.x;
    const int lane = t & 63;

    u32 s = 0;
    {
        const uint4* hp4 = (const uint4*)(hist + t * 128);
#pragma unroll 4
        for (int i = 0; i < 32; ++i) {
            uint4 h4 = hp4[i];
            s += h4.x + h4.y + h4.z + h4.w;
        }
    }
    csum[t] = s;
    suf[t] = s;
    if (t == 0) cnt_s = 0;
    __syncthreads();
    for (int off = 1; off < 1024; off <<= 1) {
        u32 v = suf[t] + ((t + off < 1024) ? suf[t + off] : 0u);
        __syncthreads();
        suf[t] = v;
        __syncthreads();
    }
    u32 above = suf[t] - csum[t];
    if (above < (u32)PRE && suf[t] >= (u32)PRE) {
        const u32* hp = hist + t * 128;
        u32 run = above;
        int bstar = t * 128;
        u32 found = 0;
        for (int b2 = 127; b2 >= 0; --b2) {
            u32 c = hp[b2];
            if (!found && run + c >= (u32)PRE) { bstar = t * 128 + b2; found = 1; }
            if (!found) run += c;
        }
        sel_s = bstar;
    }
    for (int i = t; i < SORTN; i += 1024) sk[i] = 0;
    __syncthreads();

    const int sel = sel_s;
#pragma unroll 1
    for (int u = 0; u < 9; ++u) {
        int g = t + (u << 10);
        float4 s4 = *(const float4*)(scores + (g << 2));
#pragma unroll
        for (int e = 0; e < 4; ++e) {
            u32 sb = __float_as_uint(((const float*)&s4)[e]);
            bool pred = ((int)(sb >> 13) >= sel);
            u64 bal = __ballot(pred);
            int cnt = __popcll(bal);
            int bs = 0;
            if (lane == 0 && cnt) bs = atomicAdd(&cnt_s, cnt);
            bs = __builtin_amdgcn_readfirstlane(bs);
            if (pred) {
                int p = bs + __popcll(bal & ((1ull << lane) - 1ull));
                if (p < SORTN)
                    sk[p] = ((u64)sb << 32) | (u32)(~((g << 2) + e));
            }
        }
    }
    __syncthreads();

    const int base = t << 3;
    u64 a[8];
    {
#pragma unroll
        for (int u = 0; u < 8; ++u) a[u] = sk[base + u];
#pragma unroll
        for (int k = 2; k <= 8; k <<= 1) {
#pragma unroll
            for (int j = k >> 1; j > 0; j >>= 1) {
#pragma unroll
                for (int u = 0; u < 8; ++u) {
                    if ((u & j) == 0) {
                        int l = u | j;
                        bool up = (((base + u) & k) == 0);
                        u64 x0 = a[u], x1 = a[l];
                        if (up ? (x0 < x1) : (x0 > x1)) { a[u] = x1; a[l] = x0; }
                    }
                }
            }
        }
#pragma unroll
        for (int u = 0; u < 8; ++u) sk[base + u] = a[u];
        __syncthreads();
    }
    for (int k = 16; k <= SORTN; k <<= 1) {
        for (int j = k >> 1; j >= 8; j >>= 1) {
#pragma unroll
            for (int s2 = 0; s2 < 4; ++s2) {
                int pidx = t + (s2 << 10);
                int i = ((pidx & ~(j - 1)) << 1) | (pidx & (j - 1));
                int l = i | j;
                u64 x0 = sk[i], x1 = sk[l];
                bool up = ((i & k) == 0);
                if (up ? (x0 < x1) : (x0 > x1)) { sk[i] = x1; sk[l] = x0; }
            }
            __syncthreads();
        }
#pragma unroll
        for (int u = 0; u < 8; ++u) a[u] = sk[base + u];
        {
            bool up = ((base & k) == 0);
#pragma unroll
            for (int j = 4; j > 0; j >>= 1) {
#pragma unroll
                for (int u = 0; u < 8; ++u) {
                    if ((u & j) == 0) {
                        int l = u | j;
                        u64 x0 = a[u], x1 = a[l];
                        if (up ? (x0 < x1) : (x0 > x1)) { a[u] = x1; a[l] = x0; }
                    }
                }
            }
        }
#pragma unroll
        for (int u = 0; u < 8; ++u) sk[base + u] = a[u];
        __syncthreads();
    }

    const float wimg = (float)ishape[1], himg = (float)ishape[0];
#pragma unroll 1
    for (int s2 = 0; s2 < 6; ++s2) {
        int r = (s2 << 10) + t;
        bool valid = false;
        if (r < PRE) {
            u64 key = sk[r];
            u32 sb = (u32)(key >> 32);
            int i = (int)(~(u32)key);
            topv[r] = __uint_as_float(sb);
            int c = i >> 10;
            int t4 = i & 1023;
            float4 d4 = *(const float4*)(draw + c * 4096 + (t4 << 2));
            float4 a4 = *(const float4*)(anchors + i * 4);
            float aw = a4.z - a4.x, ah = a4.w - a4.y;
            float ax = a4.x + 0.5f * aw, ay = a4.y + 0.5f * ah;
            const float CLIPV = (float)4.135166556742356;
            float dw = fminf(d4.z, CLIPV);
            float dh = fminf(d4.w, CLIPV);
            float px = d4.x * aw + ax, py = d4.y * ah + ay;
            float pw = expf(dw) * aw, ph = expf(dh) * ah;
            float x1 = fminf(fmaxf(px - 0.5f * pw, 0.f), wimg);
            float y1 = fminf(fmaxf(py - 0.5f * ph, 0.f), himg);
            float x2 = fminf(fmaxf(px + 0.5f * pw, 0.f), wimg);
            float y2 = fminf(fmaxf(py + 0.5f * ph, 0.f), himg);
            valid = (x2 - x1 >= 16.f) && (y2 - y1 >= 16.f);
            *(float4*)(boxes + r * 4) = make_float4(x1, y1, x2, y2);
        }
        u64 bm = __ballot(valid);
        if ((t & 63) == 0) vw[(s2 << 4) + (t >> 6)] = bm;
    }
}

// ================= K4: suppression bitmask (iou > 0.7, j > row) =============
__global__ __launch_bounds__(256) void k_mask(const float* __restrict__ boxes,
                                              u64* __restrict__ mask) {
    __shared__ float4 cbx[16 * 65];
    const int t = threadIdx.x;
    const int r0 = blockIdx.x << 4;
    const int row = r0 + (t >> 4);
    const int wloc = t & 15;
    float4 rb = *(const float4*)(boxes + row * 4);
    float area_a = (rb.z - rb.x) * (rb.w - rb.y);
    for (int chunk = 0; chunk < 6; ++chunk) {
        int j0c = chunk << 10;
        for (int idx = t; idx < 1024; idx += 256) {
            int j = j0c + idx;
            float4 v = make_float4(0.f, 0.f, 0.f, 0.f);
            if (j < PRE) v = *(const float4*)(boxes + j * 4);
            cbx[(idx >> 6) * 65 + (idx & 63)] = v;
        }
        __syncthreads();
        u64 bits = 0;
        const float4* cbr = cbx + wloc * 65;
        for (int b = 0; b < 64; ++b) {
            int j = j0c + (wloc << 6) + b;
            float4 ob = cbr[b];
            float area_b = (ob.z - ob.x) * (ob.w - ob.y);
            float ltx = fmaxf(rb.x, ob.x), lty = fmaxf(rb.y, ob.y);
            float rbx = fminf(rb.z, ob.z), rby = fminf(rb.w, ob.w);
            float wx = fmaxf(rbx - ltx, 0.f), wy = fmaxf(rby - lty, 0.f);
            float inter = wx * wy;
            float uni = area_a + area_b - inter;
            float iou = (uni > 0.f) ? (inter / uni) : 0.f;
            if (iou > 0.7f && j > row && j < PRE) bits |= (1ull << b);
        }
        mask[(size_t)row * MROW + (chunk << 4) + wloc] = bits;
        __syncthreads();
    }
}

// ======== K5 (v21): single-wave NMS scan, readlane, batch depth 16 ==========
__device__ __forceinline__ u64 readlane64(u64 v, int lane) {
    u32 lo = (u32)__builtin_amdgcn_readlane((int)(u32)v, lane);
    u32 hi = (u32)__builtin_amdgcn_readlane((int)(u32)(v >> 32), lane);
    return ((u64)hi << 32) | lo;
}
__global__ __launch_bounds__(320) void k_nms_out(const u64* __restrict__ mask,
                                                 const u64* __restrict__ vw,
                                                 const float* __restrict__ boxes,
                                                 const float* __restrict__ topv,
                                                 float* __restrict__ out) {
    __shared__ u64 kws[MROW];
    __shared__ int keepl[POST];
    __shared__ int kc_s;
    const int tid = threadIdx.x;
    if (tid < MROW) kws[tid] = 0ull;
    __syncthreads();

    if (tid < 64) {
        const int lane = tid;
        u64 vw0 = (lane < 94) ? vw[lane] : 0ull;
        u64 vw1 = (lane < 30) ? vw[64 + lane] : 0ull;
        u64 rem0 = 0ull, rem1 = 0ull;
        int kc = 0;
        bool done = false;
        for (int w = 0; w < 94 && !done; ++w) {
            u64 vww  = (w < 64) ? readlane64(vw0, w)  : readlane64(vw1, w - 64);
            u64 remw = (w < 64) ? readlane64(rem0, w) : readlane64(rem1, w - 64);
            u64 aw = vww & ~remw;
            u64 kwbits = 0;
            while (aw && !done) {
                int bq[NBW];
                u64 tmp = aw;
#pragma unroll
                for (int q = 0; q < NBW; ++q) {
                    bq[q] = tmp ? __builtin_ctzll(tmp) : 64;
                    tmp &= tmp - 1;
                }
                u64 rq0[NBW], rq1[NBW];
#pragma unroll
                for (int q = 0; q < NBW; ++q) {
                    rq0[q] = 0ull; rq1[q] = 0ull;
                    if (bq[q] < 64) {
                        const u64* mrow = mask + (size_t)((w << 6) + bq[q]) * MROW;
                        rq0[q] = mrow[lane];
                        if (lane < 30) rq1[q] = mrow[64 + lane];
                    }
                }
#pragma unroll
                for (int q = 0; q < NBW; ++q) {
                    int b = bq[q];
                    if (b >= 64) break;
                    if (!((aw >> b) & 1ull)) continue;
                    if (lane == 0) keepl[kc] = (w << 6) + b;
                    kc++;
                    kwbits |= (1ull << b);
                    if (kc >= POST) { done = true; break; }
                    rem0 |= rq0[q];
                    rem1 |= rq1[q];
                    u64 roww = (w < 64) ? readlane64(rq0[q], w) : readlane64(rq1[q], w - 64);
                    aw &= ~roww;
                    aw &= ~(1ull << b);
                }
            }
            if (lane == 0) kws[w] = kwbits;
        }
        if (lane == 0) kc_s = kc;
    }
    __syncthreads();

    int j = tid;
    if (j >= POST) return;
    int kc2 = kc_s;
    int r;
    float sc;
    if (j < kc2) {
        r = keepl[j];
        sc = topv[r];
    } else {
        int target = j - kc2;
        r = PRE - 1;
        int cum = 0;
        for (int w = 0; w < 94; ++w) {
            u64 kb = kws[w];
            int nvalid = (w < 93) ? 64 : 48;
            u64 vmask2 = (nvalid == 64) ? ~0ull : ((1ull << nvalid) - 1ull);
            u64 nk = (~kb) & vmask2;
            int c = __popcll(nk);
            if (cum + c > target) {
                int need = target - cum;
                u64 m = nk;
                for (int q = 0; q < need; ++q) m &= (m - 1);
                r = (w << 6) + __builtin_ctzll(m);
                break;
            }
            cum += c;
        }
        sc = -1.0f;
    }
    out[j * 4 + 0] = boxes[r * 4 + 0];
    out[j * 4 + 1] = boxes[r * 4 + 1];
    out[j * 4 + 2] = boxes[r * 4 + 2];
    out[j * 4 + 3] = boxes[r * 4 + 3];
    out[1200 + j] = sc;
}

extern "C" void kernel_launch(void* const* d_in, const int* in_sizes, int n_in,
                              void* d_out, int out_size, void* d_ws, size_t ws_size,
                              hipStream_t stream) {
    const float* x = (const float*)d_in[0];
    const float* anchors = (const float*)d_in[1];
    const int* ishape = (const int*)d_in[2];
    const float* c1w = (const float*)d_in[3];
    const float* c1b = (const float*)d_in[4];
    const float* clw = (const float*)d_in[5];
    const float* clb = (const float*)d_in[6];
    const float* bxw = (const float*)d_in[7];
    const float* bxb = (const float*)d_in[8];

    char* ws = (char*)d_ws;
    float* y      = (float*)(ws + OFF_Y);
    float* wT     = (float*)(ws + OFF_WT);
    float* zpart  = (float*)(ws + OFF_ZPART);
    float* scores = (float*)(ws + OFF_SCORES);
    float* draw   = (float*)(ws + OFF_DRAW);
    u32*   hist   = (u32*)(ws + OFF_HIST);
    float* topv   = (float*)(ws + OFF_TOPV);
    float* boxes  = (float*)(ws + OFF_BOXES);
    u64*   vw     = (u64*)(ws + OFF_VW);
    u64*   mask   = (u64*)(ws + OFF_MASK);

    k_wtrans<<<576, 256, 0, stream>>>(c1w, wT);
    k_conv1<<<2048, 256, 0, stream>>>(x, wT, c1b, y);
    k_heads_part<<<256, 256, 0, stream>>>(y, clw, bxw, zpart, hist);
    k_hreduce<<<(45 * 4096 + 255) / 256, 256, 0, stream>>>(zpart, clb, bxb, scores, draw, hist);
    k_select<<<1, 1024, 0, stream>>>(hist, scores, draw, anchors, ishape, boxes, topv, vw);
    k_mask<<<PRE / 16, 256, 0, stream>>>(boxes, mask);
    k_nms_out<<<1, 320, 0, stream>>>(mask, vw, boxes, topv, (float*)d_out);
}

// Round 18
// 639.894 us; speedup vs baseline: 1.1568x; 1.1568x over previous
//
#include <hip/hip_runtime.h>
#include <hip/hip_bf16.h>

typedef unsigned int u32;
typedef unsigned long long u64;
typedef float v2f __attribute__((ext_vector_type(2)));
typedef float v4f __attribute__((ext_vector_type(4)));

// ---------------- workspace layout (bytes) ----------------
#define OFF_Y      0ull             // 8,388,608
#define OFF_WT     8388608ull       // 9,437,184 -> end 17,825,792
#define OFF_ZPART  8388608ull       // 4*45*4096*4 = 2,949,120
#define OFF_SCORES 11337728ull      // 147,456
#define OFF_DRAW   11485184ull      // 589,824
#define OFF_HIST   12075008ull      // 524,288
#define OFF_TOPV   12665344ull      // 24,576
#define OFF_BOXES  12714496ull      // 98,304
#define OFF_VW     12812800ull      // 1,024
#define OFF_MASK   12813824ull      // 6000*96*8 = 4,608,000 -> 17,421,824

#define NS     36864
#define PRE    6000
#define POST   300
#define SORTN  8192
#define MROW   96   // mask words per row (94 used)
#define NBW    16   // nms batch: rows in flight

// ====== K0 (v17): LDS-tiled transpose gw[co][ci*9+k] -> wT[ci][k][co] =======
__global__ __launch_bounds__(256) void k_wtrans(const float* __restrict__ gw,
                                                float* __restrict__ wT) {
    __shared__ float tile[64][65];
    const int t = threadIdx.x;
    const int tr = t & 63;
    const int tc = t >> 6;
    const int bco = (blockIdx.x & 7) << 6;
    const int brr = (blockIdx.x >> 3) << 6;

#pragma unroll
    for (int i = 0; i < 16; ++i) {
        int row = tc + (i << 2);
        tile[row][tr] = gw[(size_t)(bco + row) * 4608 + brr + tr];
    }
    __syncthreads();
#pragma unroll
    for (int i = 0; i < 16; ++i) {
        int rl = tc + (i << 2);
        int rg = brr + rl;
        int ci = rg / 9;
        int k = rg - ci * 9;
        wT[(size_t)ci * 4608 + k * 512 + bco + tr] = tile[tr][rl];
    }
}

// ================= K1: 3x3 conv 512->512 + bias + relu (v15, FINAL) =========
// Measured floor: 307 us (VGPR 12, LDS 0, VALU ~58%, 4 blk/CU).
// Structure space fully probed: v7 (2 rows/2blk) 553, v8 (4co/8blk+LDS) 978,
// v10 (weights via LDS) 442, v22 (4co/8blk no-LDS) 413. 8 co/wave x 64 cols
// at 4 blk/CU is the overhead/latency-hiding optimum. x from global (vmcnt)
// + DPP wave shifts for tx+-1; weights via SGPR s_loads.
__device__ __forceinline__ float dpp_shr1(float v) {
    return __int_as_float(__builtin_amdgcn_update_dpp(
        0, __float_as_int(v), 0x138, 0xF, 0xF, true));
}
__device__ __forceinline__ float dpp_shl1(float v) {
    return __int_as_float(__builtin_amdgcn_update_dpp(
        0, __float_as_int(v), 0x130, 0xF, 0xF, true));
}
__global__ __launch_bounds__(256, 4) void k_conv1(const float* __restrict__ x,
                                                  const float* __restrict__ wT,
                                                  const float* __restrict__ gb,
                                                  float* __restrict__ y) {
    const int t = threadIdx.x;
    const int tx = t & 63;
    const int wv = __builtin_amdgcn_readfirstlane(t >> 6);
    const int cob = (blockIdx.x & 15) << 5;
    const int h0 = blockIdx.x >> 4;
    const int co_base = cob + (wv << 3);

    const bool rv0 = (h0 > 0);
    const bool rv2 = (h0 < 63);
    const float* xp0 = x + (rv0 ? (h0 - 1) : h0) * 64 + tx;
    const float* xp1 = x + h0 * 64 + tx;
    const float* xp2 = x + (rv2 ? (h0 + 1) : h0) * 64 + tx;

    v2f acc2[4];
#pragma unroll
    for (int j = 0; j < 4; ++j) acc2[j] = (v2f){0.f, 0.f};

#pragma unroll 2
    for (int ci = 0; ci < 512; ++ci) {
        float c0 = xp0[(size_t)ci * 4096];
        float c1 = xp1[(size_t)ci * 4096];
        float c2 = xp2[(size_t)ci * 4096];
        c0 = rv0 ? c0 : 0.f;
        c2 = rv2 ? c2 : 0.f;
        float xr[9];
        xr[0] = dpp_shr1(c0); xr[1] = c0; xr[2] = dpp_shl1(c0);
        xr[3] = dpp_shr1(c1); xr[4] = c1; xr[5] = dpp_shl1(c1);
        xr[6] = dpp_shr1(c2); xr[7] = c2; xr[8] = dpp_shl1(c2);

        const v2f* wk2 = (const v2f*)(wT + (size_t)ci * 4608 + co_base);
#pragma unroll
        for (int k = 0; k < 9; ++k) {
            v2f w0 = wk2[k * 256 + 0];
            v2f w1 = wk2[k * 256 + 1];
            v2f w2 = wk2[k * 256 + 2];
            v2f w3 = wk2[k * 256 + 3];
            float xv = xr[k];
            v2f xpv = {xv, xv};
            acc2[0] = __builtin_elementwise_fma(w0, xpv, acc2[0]);
            acc2[1] = __builtin_elementwise_fma(w1, xpv, acc2[1]);
            acc2[2] = __builtin_elementwise_fma(w2, xpv, acc2[2]);
            acc2[3] = __builtin_elementwise_fma(w3, xpv, acc2[3]);
        }
    }

#pragma unroll
    for (int j = 0; j < 4; ++j) {
        int co0 = co_base + 2 * j;
        float v0 = acc2[j].x + gb[co0];
        float v1 = acc2[j].y + gb[co0 + 1];
        v0 = v0 > 0.f ? v0 : 0.f;
        v1 = v1 > 0.f ? v1 : 0.f;
        y[co0 * 4096 + (h0 << 6) + tx] = v0;
        y[(co0 + 1) * 4096 + (h0 << 6) + tx] = v1;
    }
}

// ================= K2a: 1x1 heads, partial over ci quarters (9.3 us) ========
__global__ __launch_bounds__(256) void k_heads_part(const float* __restrict__ y,
                                                    const float* __restrict__ cw,
                                                    const float* __restrict__ bw,
                                                    float* __restrict__ zpart,
                                                    u32* __restrict__ hist) {
    __shared__ __align__(16) float ys[64][132];
    const int t = threadIdx.x;
    {
        int hb = blockIdx.x << 9;
        hist[hb + t] = 0u;
        hist[hb + 256 + t] = 0u;
    }
    const int px = t & 63;
    const int gu = __builtin_amdgcn_readfirstlane(t >> 6);
    const int px0 = (blockIdx.x & 63) << 6;
    const int q = blockIdx.x >> 6;
    const int cib = q << 7;
    const int nch = (gu == 0) ? 12 : 11;

    const float* wrow[12];
#pragma unroll
    for (int j = 0; j < 12; ++j) {
        int ch = gu + 4 * j;
        if (ch < 9) wrow[j] = cw + ch * 512;
        else if (ch < 45) wrow[j] = bw + (ch - 9) * 512;
        else wrow[j] = cw;
    }
    float acc[12];
#pragma unroll
    for (int j = 0; j < 12; ++j) acc[j] = 0.f;

    for (int idx = t; idx < 128 * 64; idx += 256) {
        int ci = idx >> 6;
        int pp = idx & 63;
        ys[pp][ci] = y[(cib + ci) * 4096 + px0 + pp];
    }
    __syncthreads();

#pragma unroll 1
    for (int cq = 0; cq < 32; ++cq) {
        float4 yv = *(const float4*)&ys[px][cq << 2];
        float4 wv[12];
#pragma unroll
        for (int j = 0; j < 12; ++j)
            if (j < nch) wv[j] = *(const float4*)(wrow[j] + cib + (cq << 2));
#pragma unroll
        for (int j = 0; j < 12; ++j)
            if (j < nch)
                acc[j] += wv[j].x * yv.x + wv[j].y * yv.y + wv[j].z * yv.z + wv[j].w * yv.w;
    }
    for (int j = 0; j < nch; ++j) {
        int ch = gu + 4 * j;
        zpart[((q * 45 + ch) << 12) + px0 + px] = acc[j];
    }
}

// ================= K2b: reduce partials + bias + sigmoid + hist =============
__global__ __launch_bounds__(256) void k_hreduce(const float* __restrict__ zpart,
                                                 const float* __restrict__ cb,
                                                 const float* __restrict__ bb,
                                                 float* __restrict__ scores,
                                                 float* __restrict__ draw,
                                                 u32* __restrict__ hist) {
    int i = blockIdx.x * 256 + threadIdx.x;
    if (i >= 45 * 4096) return;
    int ch = i >> 12;
    int sp = i & 4095;
    float z = zpart[((0 * 45 + ch) << 12) + sp] + zpart[((1 * 45 + ch) << 12) + sp] +
              zpart[((2 * 45 + ch) << 12) + sp] + zpart[((3 * 45 + ch) << 12) + sp];
    if (ch < 9) {
        z += cb[ch];
        float s = 1.f / (1.f + expf(-z));
        scores[(ch << 12) + sp] = s;
        u32 sb = __float_as_uint(s);
        atomicAdd(&hist[sb >> 13], 1u);
    } else {
        z += bb[ch - 9];
        draw[((ch - 9) << 12) + sp] = z;
    }
}

// ======== K3 (v18): hist-scan + compact + bitonic sort + decode (99 us) =====
__global__ __launch_bounds__(1024) void k_select(const u32* __restrict__ hist,
                                                 const float* __restrict__ scores,
                                                 const float* __restrict__ draw,
                                                 const float* __restrict__ anchors,
                                                 const int* __restrict__ ishape,
                                                 float* __restrict__ boxes,
                                                 float* __restrict__ topv,
                                                 u64* __restrict__ vw) {
    __shared__ u32 csum[1024];
    __shared__ u32 suf[1024];
    __shared__ u64 sk[SORTN];   // 64 KB
    __shared__ int sel_s, cnt_s;
    const int t = threadIdx.x;
    const int lane = t & 63;

    u32 s = 0;
    {
        const uint4* hp4 = (const uint4*)(hist + t * 128);
#pragma unroll 4
        for (int i = 0; i < 32; ++i) {
            uint4 h4 = hp4[i];
            s += h4.x + h4.y + h4.z + h4.w;
        }
    }
    csum[t] = s;
    suf[t] = s;
    if (t == 0) cnt_s = 0;
    __syncthreads();
    for (int off = 1; off < 1024; off <<= 1) {
        u32 v = suf[t] + ((t + off < 1024) ? suf[t + off] : 0u);
        __syncthreads();
        suf[t] = v;
        __syncthreads();
    }
    u32 above = suf[t] - csum[t];
    if (above < (u32)PRE && suf[t] >= (u32)PRE) {
        const u32* hp = hist + t * 128;
        u32 run = above;
        int bstar = t * 128;
        u32 found = 0;
        for (int b2 = 127; b2 >= 0; --b2) {
            u32 c = hp[b2];
            if (!found && run + c >= (u32)PRE) { bstar = t * 128 + b2; found = 1; }
            if (!found) run += c;
        }
        sel_s = bstar;
    }
    for (int i = t; i < SORTN; i += 1024) sk[i] = 0;
    __syncthreads();

    const int sel = sel_s;
#pragma unroll 1
    for (int u = 0; u < 9; ++u) {
        int g = t + (u << 10);
        float4 s4 = *(const float4*)(scores + (g << 2));
#pragma unroll
        for (int e = 0; e < 4; ++e) {
            u32 sb = __float_as_uint(((const float*)&s4)[e]);
            bool pred = ((int)(sb >> 13) >= sel);
            u64 bal = __ballot(pred);
            int cnt = __popcll(bal);
            int bs = 0;
            if (lane == 0 && cnt) bs = atomicAdd(&cnt_s, cnt);
            bs = __builtin_amdgcn_readfirstlane(bs);
            if (pred) {
                int p = bs + __popcll(bal & ((1ull << lane) - 1ull));
                if (p < SORTN)
                    sk[p] = ((u64)sb << 32) | (u32)(~((g << 2) + e));
            }
        }
    }
    __syncthreads();

    const int base = t << 3;
    u64 a[8];
    {
#pragma unroll
        for (int u = 0; u < 8; ++u) a[u] = sk[base + u];
#pragma unroll
        for (int k = 2; k <= 8; k <<= 1) {
#pragma unroll
            for (int j = k >> 1; j > 0; j >>= 1) {
#pragma unroll
                for (int u = 0; u < 8; ++u) {
                    if ((u & j) == 0) {
                        int l = u | j;
                        bool up = (((base + u) & k) == 0);
                        u64 x0 = a[u], x1 = a[l];
                        if (up ? (x0 < x1) : (x0 > x1)) { a[u] = x1; a[l] = x0; }
                    }
                }
            }
        }
#pragma unroll
        for (int u = 0; u < 8; ++u) sk[base + u] = a[u];
        __syncthreads();
    }
    for (int k = 16; k <= SORTN; k <<= 1) {
        for (int j = k >> 1; j >= 8; j >>= 1) {
#pragma unroll
            for (int s2 = 0; s2 < 4; ++s2) {
                int pidx = t + (s2 << 10);
                int i = ((pidx & ~(j - 1)) << 1) | (pidx & (j - 1));
                int l = i | j;
                u64 x0 = sk[i], x1 = sk[l];
                bool up = ((i & k) == 0);
                if (up ? (x0 < x1) : (x0 > x1)) { sk[i] = x1; sk[l] = x0; }
            }
            __syncthreads();
        }
#pragma unroll
        for (int u = 0; u < 8; ++u) a[u] = sk[base + u];
        {
            bool up = ((base & k) == 0);
#pragma unroll
            for (int j = 4; j > 0; j >>= 1) {
#pragma unroll
                for (int u = 0; u < 8; ++u) {
                    if ((u & j) == 0) {
                        int l = u | j;
                        u64 x0 = a[u], x1 = a[l];
                        if (up ? (x0 < x1) : (x0 > x1)) { a[u] = x1; a[l] = x0; }
                    }
                }
            }
        }
#pragma unroll
        for (int u = 0; u < 8; ++u) sk[base + u] = a[u];
        __syncthreads();
    }

    const float wimg = (float)ishape[1], himg = (float)ishape[0];
#pragma unroll 1
    for (int s2 = 0; s2 < 6; ++s2) {
        int r = (s2 << 10) + t;
        bool valid = false;
        if (r < PRE) {
            u64 key = sk[r];
            u32 sb = (u32)(key >> 32);
            int i = (int)(~(u32)key);
            topv[r] = __uint_as_float(sb);
            int c = i >> 10;
            int t4 = i & 1023;
            float4 d4 = *(const float4*)(draw + c * 4096 + (t4 << 2));
            float4 a4 = *(const float4*)(anchors + i * 4);
            float aw = a4.z - a4.x, ah = a4.w - a4.y;
            float ax = a4.x + 0.5f * aw, ay = a4.y + 0.5f * ah;
            const float CLIPV = (float)4.135166556742356;
            float dw = fminf(d4.z, CLIPV);
            float dh = fminf(d4.w, CLIPV);
            float px = d4.x * aw + ax, py = d4.y * ah + ay;
            float pw = expf(dw) * aw, ph = expf(dh) * ah;
            float x1 = fminf(fmaxf(px - 0.5f * pw, 0.f), wimg);
            float y1 = fminf(fmaxf(py - 0.5f * ph, 0.f), himg);
            float x2 = fminf(fmaxf(px + 0.5f * pw, 0.f), wimg);
            float y2 = fminf(fmaxf(py + 0.5f * ph, 0.f), himg);
            valid = (x2 - x1 >= 16.f) && (y2 - y1 >= 16.f);
            *(float4*)(boxes + r * 4) = make_float4(x1, y1, x2, y2);
        }
        u64 bm = __ballot(valid);
        if ((t & 63) == 0) vw[(s2 << 4) + (t >> 6)] = bm;
    }
}

// ================= K4: suppression bitmask (iou > 0.7, j > row) =============
__global__ __launch_bounds__(256) void k_mask(const float* __restrict__ boxes,
                                              u64* __restrict__ mask) {
    __shared__ float4 cbx[16 * 65];
    const int t = threadIdx.x;
    const int r0 = blockIdx.x << 4;
    const int row = r0 + (t >> 4);
    const int wloc = t & 15;
    float4 rb = *(const float4*)(boxes + row * 4);
    float area_a = (rb.z - rb.x) * (rb.w - rb.y);
    for (int chunk = 0; chunk < 6; ++chunk) {
        int j0c = chunk << 10;
        for (int idx = t; idx < 1024; idx += 256) {
            int j = j0c + idx;
            float4 v = make_float4(0.f, 0.f, 0.f, 0.f);
            if (j < PRE) v = *(const float4*)(boxes + j * 4);
            cbx[(idx >> 6) * 65 + (idx & 63)] = v;
        }
        __syncthreads();
        u64 bits = 0;
        const float4* cbr = cbx + wloc * 65;
        for (int b = 0; b < 64; ++b) {
            int j = j0c + (wloc << 6) + b;
            float4 ob = cbr[b];
            float area_b = (ob.z - ob.x) * (ob.w - ob.y);
            float ltx = fmaxf(rb.x, ob.x), lty = fmaxf(rb.y, ob.y);
            float rbx = fminf(rb.z, ob.z), rby = fminf(rb.w, ob.w);
            float wx = fmaxf(rbx - ltx, 0.f), wy = fmaxf(rby - lty, 0.f);
            float inter = wx * wy;
            float uni = area_a + area_b - inter;
            float iou = (uni > 0.f) ? (inter / uni) : 0.f;
            if (iou > 0.7f && j > row && j < PRE) bits |= (1ull << b);
        }
        mask[(size_t)row * MROW + (chunk << 4) + wloc] = bits;
        __syncthreads();
    }
}

// ======== K5 (v21): single-wave NMS scan, readlane, batch depth 16 ==========
__device__ __forceinline__ u64 readlane64(u64 v, int lane) {
    u32 lo = (u32)__builtin_amdgcn_readlane((int)(u32)v, lane);
    u32 hi = (u32)__builtin_amdgcn_readlane((int)(u32)(v >> 32), lane);
    return ((u64)hi << 32) | lo;
}
__global__ __launch_bounds__(320) void k_nms_out(const u64* __restrict__ mask,
                                                 const u64* __restrict__ vw,
                                                 const float* __restrict__ boxes,
                                                 const float* __restrict__ topv,
                                                 float* __restrict__ out) {
    __shared__ u64 kws[MROW];
    __shared__ int keepl[POST];
    __shared__ int kc_s;
    const int tid = threadIdx.x;
    if (tid < MROW) kws[tid] = 0ull;
    __syncthreads();

    if (tid < 64) {
        const int lane = tid;
        u64 vw0 = (lane < 94) ? vw[lane] : 0ull;
        u64 vw1 = (lane < 30) ? vw[64 + lane] : 0ull;
        u64 rem0 = 0ull, rem1 = 0ull;
        int kc = 0;
        bool done = false;
        for (int w = 0; w < 94 && !done; ++w) {
            u64 vww  = (w < 64) ? readlane64(vw0, w)  : readlane64(vw1, w - 64);
            u64 remw = (w < 64) ? readlane64(rem0, w) : readlane64(rem1, w - 64);
            u64 aw = vww & ~remw;
            u64 kwbits = 0;
            while (aw && !done) {
                int bq[NBW];
                u64 tmp = aw;
#pragma unroll
                for (int q = 0; q < NBW; ++q) {
                    bq[q] = tmp ? __builtin_ctzll(tmp) : 64;
                    tmp &= tmp - 1;
                }
                u64 rq0[NBW], rq1[NBW];
#pragma unroll
                for (int q = 0; q < NBW; ++q) {
                    rq0[q] = 0ull; rq1[q] = 0ull;
                    if (bq[q] < 64) {
                        const u64* mrow = mask + (size_t)((w << 6) + bq[q]) * MROW;
                        rq0[q] = mrow[lane];
                        if (lane < 30) rq1[q] = mrow[64 + lane];
                    }
                }
#pragma unroll
                for (int q = 0; q < NBW; ++q) {
                    int b = bq[q];
                    if (b >= 64) break;
                    if (!((aw >> b) & 1ull)) continue;
                    if (lane == 0) keepl[kc] = (w << 6) + b;
                    kc++;
                    kwbits |= (1ull << b);
                    if (kc >= POST) { done = true; break; }
                    rem0 |= rq0[q];
                    rem1 |= rq1[q];
                    u64 roww = (w < 64) ? readlane64(rq0[q], w) : readlane64(rq1[q], w - 64);
                    aw &= ~roww;
                    aw &= ~(1ull << b);
                }
            }
            if (lane == 0) kws[w] = kwbits;
        }
        if (lane == 0) kc_s = kc;
    }
    __syncthreads();

    int j = tid;
    if (j >= POST) return;
    int kc2 = kc_s;
    int r;
    float sc;
    if (j < kc2) {
        r = keepl[j];
        sc = topv[r];
    } else {
        int target = j - kc2;
        r = PRE - 1;
        int cum = 0;
        for (int w = 0; w < 94; ++w) {
            u64 kb = kws[w];
            int nvalid = (w < 93) ? 64 : 48;
            u64 vmask2 = (nvalid == 64) ? ~0ull : ((1ull << nvalid) - 1ull);
            u64 nk = (~kb) & vmask2;
            int c = __popcll(nk);
            if (cum + c > target) {
                int need = target - cum;
                u64 m = nk;
                for (int q = 0; q < need; ++q) m &= (m - 1);
                r = (w << 6) + __builtin_ctzll(m);
                break;
            }
            cum += c;
        }
        sc = -1.0f;
    }
    out[j * 4 + 0] = boxes[r * 4 + 0];
    out[j * 4 + 1] = boxes[r * 4 + 1];
    out[j * 4 + 2] = boxes[r * 4 + 2];
    out[j * 4 + 3] = boxes[r * 4 + 3];
    out[1200 + j] = sc;
}

extern "C" void kernel_launch(void* const* d_in, const int* in_sizes, int n_in,
                              void* d_out, int out_size, void* d_ws, size_t ws_size,
                              hipStream_t stream) {
    const float* x = (const float*)d_in[0];
    const float* anchors = (const float*)d_in[1];
    const int* ishape = (const int*)d_in[2];
    const float* c1w = (const float*)d_in[3];
    const float* c1b = (const float*)d_in[4];
    const float* clw = (const float*)d_in[5];
    const float* clb = (const float*)d_in[6];
    const float* bxw = (const float*)d_in[7];
    const float* bxb = (const float*)d_in[8];

    char* ws = (char*)d_ws;
    float* y      = (float*)(ws + OFF_Y);
    float* wT     = (float*)(ws + OFF_WT);
    float* zpart  = (float*)(ws + OFF_ZPART);
    float* scores = (float*)(ws + OFF_SCORES);
    float* draw   = (float*)(ws + OFF_DRAW);
    u32*   hist   = (u32*)(ws + OFF_HIST);
    float* topv   = (float*)(ws + OFF_TOPV);
    float* boxes  = (float*)(ws + OFF_BOXES);
    u64*   vw     = (u64*)(ws + OFF_VW);
    u64*   mask   = (u64*)(ws + OFF_MASK);

    k_wtrans<<<576, 256, 0, stream>>>(c1w, wT);
    k_conv1<<<1024, 256, 0, stream>>>(x, wT, c1b, y);
    k_heads_part<<<256, 256, 0, stream>>>(y, clw, bxw, zpart, hist);
    k_hreduce<<<(45 * 4096 + 255) / 256, 256, 0, stream>>>(zpart, clb, bxb, scores, draw, hist);
    k_select<<<1, 1024, 0, stream>>>(hist, scores, draw, anchors, ishape, boxes, topv, vw);
    k_mask<<<PRE / 16, 256, 0, stream>>>(boxes, mask);
    k_nms_out<<<1, 320, 0, stream>>>(mask, vw, boxes, topv, (float*)d_out);
}